// Round 1
// baseline (5569.655 us; speedup 1.0000x reference)
//
#include <hip/hip_runtime.h>
#include <stdint.h>

// ---------------------------------------------------------------------------
// FixedPointLSTM (B=64, T=256, I=512, H=1024), fixed-point Q8.8 with hard
// activations. All fxp grid values are exactly representable in fp16, and all
// fp32 accumulations are exact (integers/65536 < 2^24), so fp16 MFMA with fp32
// accumulate reproduces the numpy reference bitwise.
// ---------------------------------------------------------------------------

typedef _Float16 h8 __attribute__((ext_vector_type(8)));
typedef _Float16 h4 __attribute__((ext_vector_type(4)));
typedef float f4 __attribute__((ext_vector_type(4)));

#define MFMA16(a, b, c) __builtin_amdgcn_mfma_f32_16x16x32_f16(a, b, c, 0, 0, 0)

__device__ __forceinline__ float fxp(float x) {
  // round half-to-even to 1/256 grid, clamp to Q8.8 range
  float q = rintf(x * 256.0f) * 0.00390625f;
  return fminf(fmaxf(q, -128.0f), 127.99609375f);
}

__device__ __forceinline__ float hsig(float x) {
  return fminf(fmaxf(x / 6.0f + 0.5f, 0.0f), 1.0f);  // IEEE div to match np
}

// ---- quantize fp32 -> fxp grid, store fp16 (exact: |values| << 8) ----------
__global__ void qf16_kernel(const float* __restrict__ in,
                            _Float16* __restrict__ out, int n4) {
  int i = blockIdx.x * 256 + threadIdx.x;
  if (i < n4) {
    float4 v = ((const float4*)in)[i];
    h4 o;
    o[0] = (_Float16)fxp(v.x); o[1] = (_Float16)fxp(v.y);
    o[2] = (_Float16)fxp(v.z); o[3] = (_Float16)fxp(v.w);
    ((h4*)out)[i] = o;
  }
}

__global__ void qf32_kernel(const float* __restrict__ in,
                            float* __restrict__ out, int n4) {
  int i = blockIdx.x * 256 + threadIdx.x;
  if (i < n4) {
    float4 v = ((const float4*)in)[i];
    float4 o;
    o.x = fxp(v.x); o.y = fxp(v.y); o.z = fxp(v.z); o.w = fxp(v.w);
    ((float4*)out)[i] = o;
  }
}

// ---- async global->LDS helper (width 16B; LDS dest = wave-uniform base) ----
__device__ __forceinline__ void gload_lds16(const _Float16* g, _Float16* l) {
  __builtin_amdgcn_global_load_lds(
      (const __attribute__((address_space(1))) uint32_t*)g,
      (__attribute__((address_space(3))) uint32_t*)l, 16, 0, 0);
}

// ---------------------------------------------------------------------------
// gx = fxp(x_q @ w_ih_q^T + b_ih_q), stored fp16 as [T=256][B=64][4H=4096].
// M=16384 (m = b*256+t), N=4096, K=512. m97-style 128x128 tile, BK=32.
// ---------------------------------------------------------------------------
__global__ __launch_bounds__(256) void gemm_gx_kernel(
    const _Float16* __restrict__ Xq,   // [16384][512]
    const _Float16* __restrict__ Wih,  // [4096][512]
    const float* __restrict__ bih,     // [4096]
    _Float16* __restrict__ gx)         // [256][64][4096]
{
  __shared__ _Float16 As[128 * 32];
  __shared__ _Float16 Bs[128 * 32];
  const int tid = threadIdx.x;
  const int lane = tid & 63;
  const int w = tid >> 6;
  const int wm = (w >> 1) * 64;
  const int wn = (w & 1) * 64;
  const int m0 = blockIdx.x * 128;
  const int n0 = blockIdx.y * 128;
  const int cl = lane & 15, q = lane >> 4;

  f4 acc[4][4] = {};

  for (int k0 = 0; k0 < 512; k0 += 32) {
#pragma unroll
    for (int i = 0; i < 2; i++) {
      int idx = i * 256 + tid;
      int row = idx >> 2;
      int kc = (idx & 3) << 3;
      int wbase = (i * 256 + (tid & 192)) << 3;  // wave-uniform LDS base (halves)
      gload_lds16(Xq + (size_t)(m0 + row) * 512 + k0 + kc, As + wbase);
      gload_lds16(Wih + (size_t)(n0 + row) * 512 + k0 + kc, Bs + wbase);
    }
    __syncthreads();
    h8 af[4], bf[4];
#pragma unroll
    for (int mt = 0; mt < 4; mt++)
      af[mt] = *(const h8*)(As + (wm + mt * 16 + cl) * 32 + q * 8);
#pragma unroll
    for (int nt = 0; nt < 4; nt++)
      bf[nt] = *(const h8*)(Bs + (wn + nt * 16 + cl) * 32 + q * 8);
#pragma unroll
    for (int mt = 0; mt < 4; mt++)
#pragma unroll
      for (int nt = 0; nt < 4; nt++)
        acc[mt][nt] = MFMA16(af[mt], bf[nt], acc[mt][nt]);
    __syncthreads();
  }

#pragma unroll
  for (int nt = 0; nt < 4; nt++) {
    const int n = n0 + wn + nt * 16 + cl;
    const float bv = bih[n];
#pragma unroll
    for (int mt = 0; mt < 4; mt++) {
#pragma unroll
      for (int r = 0; r < 4; r++) {
        int m = m0 + wm + mt * 16 + q * 4 + r;
        float v = fxp(acc[mt][nt][r] + bv);
        int b = m >> 8, tt = m & 255;  // m = b*256 + t
        gx[(((size_t)(tt << 6) + b) << 12) + n] = (_Float16)v;
      }
    }
  }
}

// ---------------------------------------------------------------------------
// Persistent recurrence kernel. 128 blocks x 256 threads (4 waves, 1/SIMD).
// Block b owns h-columns j0..j0+7 across all 4 gates (32 W_hh rows), with the
// 32x1024 fp16 weight slice held in 256 VGPRs/wave for all 256 steps.
// Wave w handles batch rows w*16..w*16+15. h double-buffered in global fp16;
// monotonic-counter barrier per step (relaxed poll, release add, acquire
// fence) for cross-XCD visibility. c-state and last-h live in registers.
// ---------------------------------------------------------------------------
__global__ __launch_bounds__(256, 1) void lstm_kernel(
    const _Float16* __restrict__ Whh,  // [4096][1024] quantized
    const float* __restrict__ bhh,     // [4096] quantized
    const _Float16* __restrict__ gx,   // [256][64][4096]
    const float* __restrict__ c0,      // [64][1024]
    _Float16* __restrict__ hbuf,       // [2][64][1024]
    float* __restrict__ out,           // [64][256][1024] ++ h_n ++ c_n
    unsigned* __restrict__ cnt)
{
  const int tid = threadIdx.x;
  const int lane = tid & 63;
  const int w = tid >> 6;
  const int cl = lane & 15, q = lane >> 4;
  const int j0 = blockIdx.x << 3;
  const int g01 = cl >> 3;                         // 0/1 within tile
  const int row0 = (g01 << 10) + j0 + (cl & 7);    // gate i/f column (tile0)
  const int row1 = ((g01 + 2) << 10) + j0 + (cl & 7);  // gate g/o column (tile1)

  // persistent B fragments: 2 tiles x 32 k-steps x 4 VGPRs = 256 VGPRs
  h8 B0[32], B1[32];
#pragma unroll
  for (int kt = 0; kt < 32; kt++) {
    B0[kt] = *(const h8*)(Whh + (size_t)row0 * 1024 + (kt << 5) + (q << 3));
    B1[kt] = *(const h8*)(Whh + (size_t)row1 * 1024 + (kt << 5) + (q << 3));
  }
  const float bh0 = bhh[row0], bh1 = bhh[row1];
  const int jc = j0 + (lane & 7);
  const int mrow = (w << 4) + (q << 2);  // this lane's acc rows: mrow..mrow+3
  const int arow = (w << 4) + cl;        // this lane's A-fragment row
  const bool writer = (lane & 8) == 0;

  float c_st[4], h_last[4];
#pragma unroll
  for (int r = 0; r < 4; r++) {
    c_st[r] = c0[(mrow + r) * 1024 + jc];  // c0 used raw (matches reference)
    h_last[r] = 0.0f;
  }

  for (int t = 0; t < 256; t++) {
    // prefetch gx_t (independent of peer blocks -> overlaps the spin)
    float gxa[4], gxb[4];
    {
      const _Float16* gxt = gx + ((size_t)t << 18);
#pragma unroll
      for (int r = 0; r < 4; r++) {
        gxa[r] = (float)gxt[((size_t)(mrow + r) << 12) + row0];
        gxb[r] = (float)gxt[((size_t)(mrow + r) << 12) + row1];
      }
    }
    if (t) {
      if (tid == 0) {
        unsigned target = (unsigned)t << 7;  // 128*t arrivals
        while (__hip_atomic_load(cnt, __ATOMIC_RELAXED,
                                 __HIP_MEMORY_SCOPE_AGENT) < target) {}
      }
      __syncthreads();
      __threadfence();  // acquire: invalidate caches before reading peers' h
    }

    const _Float16* hb = hbuf + ((t & 1) << 16);
    f4 a0 = {}, a1 = {}, a2 = {}, a3 = {};  // k-split accs: 4 indep MFMA chains
#pragma unroll
    for (int kt = 0; kt < 32; kt++) {
      h8 av = *(const h8*)(hb + (size_t)arow * 1024 + (kt << 5) + (q << 3));
      if (kt & 1) { a1 = MFMA16(av, B0[kt], a1); a3 = MFMA16(av, B1[kt], a3); }
      else        { a0 = MFMA16(av, B0[kt], a0); a2 = MFMA16(av, B1[kt], a2); }
    }
    f4 g0 = a0 + a1;  // exact: partials are integers/65536 < 2^24
    f4 g1 = a2 + a3;

    _Float16* hw = hbuf + (((t + 1) & 1) << 16);
#pragma unroll
    for (int r = 0; r < 4; r++) {
      float gv0 = fxp(gxa[r] + fxp(g0[r] + bh0));  // i or f preact
      float gv1 = fxp(gxb[r] + fxp(g1[r] + bh1));  // g or o preact
      float s0 = fxp(hsig(gv0));                           // i (cl<8) / f
      float s1t = fxp(fminf(fmaxf(gv1, -1.0f), 1.0f));     // g (hard_tanh)
      float s1s = fxp(hsig(gv1));                          // o
      float s1 = (lane & 8) ? s1s : s1t;
      float p0 = __shfl_xor(s0, 8);
      float p1 = __shfl_xor(s1, 8);
      float iv = writer ? s0 : p0;
      float fv = writer ? p0 : s0;
      float gv = writer ? s1 : p1;
      float ov = writer ? p1 : s1;
      float cn = fxp(fv * c_st[r] + iv * gv);  // exact products
      c_st[r] = cn;
      // fxp(hard_tanh(cn)) == hard_tanh(cn): already on 1/256 grid in [-1,1]
      float hn = fxp(ov * fminf(fmaxf(cn, -1.0f), 1.0f));
      h_last[r] = hn;
      if (writer) {
        hw[(size_t)(mrow + r) * 1024 + jc] = (_Float16)hn;
        out[((size_t)(mrow + r) * 256 + t) * 1024 + jc] = hn;
      }
    }
    __syncthreads();
    if (tid == 0)
      __hip_atomic_fetch_add(cnt, 1u, __ATOMIC_RELEASE,
                             __HIP_MEMORY_SCOPE_AGENT);
  }

  if (writer) {
#pragma unroll
    for (int r = 0; r < 4; r++) {
      out[16777216 + (size_t)(mrow + r) * 1024 + jc] = h_last[r];          // h_n
      out[16777216 + 65536 + (size_t)(mrow + r) * 1024 + jc] = c_st[r];    // c_n
    }
  }
}

// ---------------------------------------------------------------------------
extern "C" void kernel_launch(void* const* d_in, const int* in_sizes, int n_in,
                              void* d_out, int out_size, void* d_ws,
                              size_t ws_size, hipStream_t stream) {
  const float* x    = (const float*)d_in[0];
  const float* w_ih = (const float*)d_in[1];
  const float* w_hh = (const float*)d_in[2];
  const float* b_ih = (const float*)d_in[3];
  const float* b_hh = (const float*)d_in[4];
  const float* h0   = (const float*)d_in[5];
  const float* c0   = (const float*)d_in[6];
  float* out = (float*)d_out;

  // workspace layout (bytes); total ~156.3 MB
  char* ws = (char*)d_ws;
  unsigned* cnt   = (unsigned*)ws;                       // 256 B
  _Float16* hbuf  = (_Float16*)(ws + 256);               // 2*64*1024*2 = 256 KB
  _Float16* whhq  = (_Float16*)(ws + 262400);            // 4096*1024*2 = 8 MB
  _Float16* wihq  = (_Float16*)(ws + 8651008);           // 4096*512*2  = 4 MB
  float*    bihq  = (float*)(ws + 12845312);             // 16 KB
  float*    bhhq  = (float*)(ws + 12861696);             // 16 KB
  _Float16* xq    = (_Float16*)(ws + 12878080);          // 16384*512*2 = 16 MB
  _Float16* gxb   = (_Float16*)(ws + 29655296);          // 256*64*4096*2 = 128 MB

  hipMemsetAsync(cnt, 0, 256, stream);
  qf16_kernel<<<dim3(4096), 256, 0, stream>>>(w_hh, whhq, 4194304 / 4);
  qf16_kernel<<<dim3(2048), 256, 0, stream>>>(w_ih, wihq, 2097152 / 4);
  qf16_kernel<<<dim3(8192), 256, 0, stream>>>(x, xq, 8388608 / 4);
  qf16_kernel<<<dim3(64), 256, 0, stream>>>(h0, hbuf, 65536 / 4);   // h buffer 0
  qf32_kernel<<<dim3(4), 256, 0, stream>>>(b_ih, bihq, 4096 / 4);
  qf32_kernel<<<dim3(4), 256, 0, stream>>>(b_hh, bhhq, 4096 / 4);
  gemm_gx_kernel<<<dim3(128, 32), 256, 0, stream>>>(xq, wihq, bihq, gxb);
  lstm_kernel<<<dim3(128), 256, 0, stream>>>(whhq, bhhq, gxb, c0, hbuf, out,
                                             cnt);
}

// Round 2
// 5360.220 us; speedup vs baseline: 1.0391x; 1.0391x over previous
//
#include <hip/hip_runtime.h>
#include <stdint.h>

// ---------------------------------------------------------------------------
// FixedPointLSTM (B=64, T=256, I=512, H=1024), fixed-point Q8.8 with hard
// activations. All fxp grid values are exactly representable in fp16; fp16
// MFMA with fp32 accumulate matches the numpy reference to ~1 grid step.
//
// R2: latency-bound recurrence attacked via (a) parallel flag-array barrier
// (release-store per block, no atomic RMW serialization), (b) L2-bypass
// agent-scope h stores + nontemporal out stores (release wbl2 finds nothing
// dirty), (c) gx repacked [t][blk][tid][8] so the per-step gx read is one
// coalesced 16B load per lane (was 8x 2B scattered at 8KB stride).
// ---------------------------------------------------------------------------

typedef _Float16 h8 __attribute__((ext_vector_type(8)));
typedef _Float16 h4 __attribute__((ext_vector_type(4)));
typedef float f4 __attribute__((ext_vector_type(4)));

#define MFMA16(a, b, c) __builtin_amdgcn_mfma_f32_16x16x32_f16(a, b, c, 0, 0, 0)

__device__ __forceinline__ float fxp(float x) {
  float q = rintf(x * 256.0f) * 0.00390625f;
  return fminf(fmaxf(q, -128.0f), 127.99609375f);
}

__device__ __forceinline__ float hsig(float x) {
  return fminf(fmaxf(x / 6.0f + 0.5f, 0.0f), 1.0f);  // IEEE div to match np
}

// ---- quantize fp32 -> fxp grid, store fp16 ---------------------------------
__global__ void qf16_kernel(const float* __restrict__ in,
                            _Float16* __restrict__ out, int n4) {
  int i = blockIdx.x * 256 + threadIdx.x;
  if (i < n4) {
    float4 v = ((const float4*)in)[i];
    h4 o;
    o[0] = (_Float16)fxp(v.x); o[1] = (_Float16)fxp(v.y);
    o[2] = (_Float16)fxp(v.z); o[3] = (_Float16)fxp(v.w);
    ((h4*)out)[i] = o;
  }
}

// quantize + transpose x: in [64][256][512] -> out rows m = t*64+b, [16384][512]
__global__ void qx_kernel(const float* __restrict__ in,
                          _Float16* __restrict__ out) {
  int i4 = blockIdx.x * 256 + threadIdx.x;  // over 16384*128 float4s
  int col4 = i4 & 127;
  int row = i4 >> 7;  // b*256 + t
  int b = row >> 8, tt = row & 255;
  float4 v = ((const float4*)in)[i4];
  h4 o;
  o[0] = (_Float16)fxp(v.x); o[1] = (_Float16)fxp(v.y);
  o[2] = (_Float16)fxp(v.z); o[3] = (_Float16)fxp(v.w);
  ((h4*)out)[(size_t)((tt << 6) + b) * 128 + col4] = o;
}

__global__ void qf32_kernel(const float* __restrict__ in,
                            float* __restrict__ out, int n4) {
  int i = blockIdx.x * 256 + threadIdx.x;
  if (i < n4) {
    float4 v = ((const float4*)in)[i];
    float4 o;
    o.x = fxp(v.x); o.y = fxp(v.y); o.z = fxp(v.z); o.w = fxp(v.w);
    ((float4*)out)[i] = o;
  }
}

// ---- async global->LDS helper (width 16B; LDS dest = wave-uniform base) ----
__device__ __forceinline__ void gload_lds16(const _Float16* g, _Float16* l) {
  __builtin_amdgcn_global_load_lds(
      (const __attribute__((address_space(1))) uint32_t*)g,
      (__attribute__((address_space(3))) uint32_t*)l, 16, 0, 0);
}

// ---------------------------------------------------------------------------
// gx = fxp(x_q @ w_ih_q^T + b_ih_q), packed [T=256][blk=128][tid=256][8] fp16.
// M=16384 (m = t*64+b), N=4096, K=512. m97-style 128x128 tile, BK=32.
// slot layout per 16B entry: [tile0 r2=0..3 | tile1 r2=0..3], tile = gate>>1,
// r2 = b&3, tid = (b>>4)*64 + ((b>>2)&3)*16 + (gate&1)*8 + (j&7), blk = j>>3.
// Each lane packs 4 slots into one 8B store (n-block spans a single gate).
// ---------------------------------------------------------------------------
__global__ __launch_bounds__(256) void gemm_gx_kernel(
    const _Float16* __restrict__ Xq,   // [16384][512], m = t*64+b
    const _Float16* __restrict__ Wih,  // [4096][512]
    const float* __restrict__ bih,     // [4096]
    _Float16* __restrict__ gx)         // packed, see above
{
  __shared__ _Float16 As[128 * 32];
  __shared__ _Float16 Bs[128 * 32];
  const int tid = threadIdx.x;
  const int lane = tid & 63;
  const int w = tid >> 6;
  const int wm = (w >> 1) * 64;
  const int wn = (w & 1) * 64;
  const int m0 = blockIdx.x * 128;
  const int n0 = blockIdx.y * 128;
  const int cl = lane & 15, q = lane >> 4;

  f4 acc[4][4] = {};

  for (int k0 = 0; k0 < 512; k0 += 32) {
#pragma unroll
    for (int i = 0; i < 2; i++) {
      int idx = i * 256 + tid;
      int row = idx >> 2;
      int kc = (idx & 3) << 3;
      int wbase = (i * 256 + (tid & 192)) << 3;  // wave-uniform LDS base
      gload_lds16(Xq + (size_t)(m0 + row) * 512 + k0 + kc, As + wbase);
      gload_lds16(Wih + (size_t)(n0 + row) * 512 + k0 + kc, Bs + wbase);
    }
    __syncthreads();
    h8 af[4], bf[4];
#pragma unroll
    for (int mt = 0; mt < 4; mt++)
      af[mt] = *(const h8*)(As + (wm + mt * 16 + cl) * 32 + q * 8);
#pragma unroll
    for (int nt = 0; nt < 4; nt++)
      bf[nt] = *(const h8*)(Bs + (wn + nt * 16 + cl) * 32 + q * 8);
#pragma unroll
    for (int mt = 0; mt < 4; mt++)
#pragma unroll
      for (int nt = 0; nt < 4; nt++)
        acc[mt][nt] = MFMA16(af[mt], bf[nt], acc[mt][nt]);
    __syncthreads();
  }

  const int g = n0 >> 10;           // whole n-block lies in one gate
  const int tile = g >> 1;
#pragma unroll
  for (int nt = 0; nt < 4; nt++) {
    const int n = n0 + wn + nt * 16 + cl;
    const float bv = bih[n];
    const int j = n & 1023;
    const int blk = j >> 3;
    const int cl2 = ((g & 1) << 3) | (j & 7);
#pragma unroll
    for (int mt = 0; mt < 4; mt++) {
      const int mb = wm + mt * 16 + q * 4;  // m = m0+mb+r, 4-aligned
      const int m = m0 + mb;
      const int b = m & 63, tt = m >> 6;    // b also 4-aligned; r2 = r
      const int tid2 = ((b >> 4) << 6) | (((b >> 2) & 3) << 4) | cl2;
      h4 pk;
#pragma unroll
      for (int r = 0; r < 4; r++) pk[r] = (_Float16)fxp(acc[mt][nt][r] + bv);
      *(h4*)(gx + ((((size_t)tt * 128 + blk) * 256 + tid2) << 3) + (tile << 2)) = pk;
    }
  }
}

// ---------------------------------------------------------------------------
// Persistent recurrence kernel. 128 blocks x 256 threads (4 waves, 1/SIMD).
// Block b owns h-columns j0..j0+7 across all 4 gates (32 W_hh rows) held in
// 256 regs/wave for all 256 steps. Wave w handles batch rows w*16..w*16+15.
// Per-step sync: each block release-stores t+1 to flags[blk] (parallel
// arrivals); wave 0 polls all 128 flags (one 8B agent load/lane), then
// acquire fence. h communicated via L2-bypass agent-scope stores.
// ---------------------------------------------------------------------------
__global__ __launch_bounds__(256, 1) void lstm_kernel(
    const _Float16* __restrict__ Whh,  // [4096][1024] quantized
    const float* __restrict__ bhh,     // [4096] quantized
    const _Float16* __restrict__ gx,   // packed [256][128][256][8]
    const float* __restrict__ c0,      // [64][1024]
    _Float16* __restrict__ hbuf,       // [2][64][1024]
    float* __restrict__ out,           // [64][256][1024] ++ h_n ++ c_n
    unsigned* __restrict__ flags)      // [128]
{
  const int tid = threadIdx.x;
  const int lane = tid & 63;
  const int w = tid >> 6;
  const int cl = lane & 15, q = lane >> 4;
  const int j0 = blockIdx.x << 3;
  const int g01 = cl >> 3;
  const int row0 = (g01 << 10) + j0 + (cl & 7);        // gates i/f
  const int row1 = ((g01 + 2) << 10) + j0 + (cl & 7);  // gates g/o

  // persistent B fragments: 2 tiles x 32 k-steps x 4 VGPRs = 256 regs
  h8 B0[32], B1[32];
#pragma unroll
  for (int kt = 0; kt < 32; kt++) {
    B0[kt] = *(const h8*)(Whh + (size_t)row0 * 1024 + (kt << 5) + (q << 3));
    B1[kt] = *(const h8*)(Whh + (size_t)row1 * 1024 + (kt << 5) + (q << 3));
  }
  const float bh0 = bhh[row0], bh1 = bhh[row1];
  const int jc = j0 + (lane & 7);
  const int mrow = (w << 4) + (q << 2);
  const int arow = (w << 4) + cl;
  const bool writer = (lane & 8) == 0;

  float c_st[4], h_last[4];
#pragma unroll
  for (int r = 0; r < 4; r++) {
    c_st[r] = c0[(mrow + r) * 1024 + jc];
    h_last[r] = 0.0f;
  }

  for (int t = 0; t < 256; t++) {
    // prefetch gx_t: one coalesced 16B load per lane (overlaps the spin)
    const h8 gv8 =
        *(const h8*)(gx + ((((size_t)t * 128 + blockIdx.x) * 256 + tid) << 3));

    if (t) {
      if (w == 0) {
        const unsigned long long* f2 = (const unsigned long long*)flags;
        const unsigned tt = (unsigned)t;
        for (;;) {
          unsigned long long v = __hip_atomic_load(
              &f2[lane], __ATOMIC_RELAXED, __HIP_MEMORY_SCOPE_AGENT);
          bool ok = ((unsigned)v >= tt) && ((unsigned)(v >> 32) >= tt);
          if (__ballot(ok) == ~0ull) break;
        }
      }
      __syncthreads();
      __threadfence();  // acquire: pairs with peers' release flag stores
    }

    const _Float16* hb = hbuf + ((t & 1) << 16);
    f4 a0 = {}, a1 = {}, a2 = {}, a3 = {};
#pragma unroll
    for (int kt = 0; kt < 32; kt++) {
      h8 av = *(const h8*)(hb + (size_t)arow * 1024 + (kt << 5) + (q << 3));
      if (kt & 1) { a1 = MFMA16(av, B0[kt], a1); a3 = MFMA16(av, B1[kt], a3); }
      else        { a0 = MFMA16(av, B0[kt], a0); a2 = MFMA16(av, B1[kt], a2); }
    }
    f4 g0 = a0 + a1;
    f4 g1 = a2 + a3;

    _Float16* hw = hbuf + (((t + 1) & 1) << 16);
#pragma unroll
    for (int r = 0; r < 4; r++) {
      float gv0 = fxp((float)gv8[r] + fxp(g0[r] + bh0));      // i or f
      float gv1 = fxp((float)gv8[4 + r] + fxp(g1[r] + bh1));  // g or o
      float s0 = fxp(hsig(gv0));
      float s1t = fxp(fminf(fmaxf(gv1, -1.0f), 1.0f));
      float s1s = fxp(hsig(gv1));
      float s1 = (lane & 8) ? s1s : s1t;
      float p0 = __shfl_xor(s0, 8);
      float p1 = __shfl_xor(s1, 8);
      float iv = writer ? s0 : p0;
      float fv = writer ? p0 : s0;
      float gv = writer ? s1 : p1;
      float ov = writer ? p1 : s1;
      float cn = fxp(fv * c_st[r] + iv * gv);
      c_st[r] = cn;
      float hn = fxp(ov * fminf(fmaxf(cn, -1.0f), 1.0f));
      h_last[r] = hn;
      if (writer) {
        // L2-bypass store: visible at agent coherence point, nothing dirty
        unsigned short hbits = __builtin_bit_cast(unsigned short, (_Float16)hn);
        __hip_atomic_store((unsigned short*)&hw[(size_t)(mrow + r) * 1024 + jc],
                           hbits, __ATOMIC_RELAXED, __HIP_MEMORY_SCOPE_AGENT);
        __builtin_nontemporal_store(
            hn, &out[((size_t)(mrow + r) * 256 + t) * 1024 + jc]);
      }
    }
    __syncthreads();  // drains all waves' stores (vmcnt(0) before s_barrier)
    if (tid == 0)
      __hip_atomic_store(&flags[blockIdx.x], (unsigned)(t + 1),
                         __ATOMIC_RELEASE, __HIP_MEMORY_SCOPE_AGENT);
  }

  if (writer) {
#pragma unroll
    for (int r = 0; r < 4; r++) {
      out[16777216 + (size_t)(mrow + r) * 1024 + jc] = h_last[r];        // h_n
      out[16777216 + 65536 + (size_t)(mrow + r) * 1024 + jc] = c_st[r];  // c_n
    }
  }
}

// ---------------------------------------------------------------------------
extern "C" void kernel_launch(void* const* d_in, const int* in_sizes, int n_in,
                              void* d_out, int out_size, void* d_ws,
                              size_t ws_size, hipStream_t stream) {
  const float* x    = (const float*)d_in[0];
  const float* w_ih = (const float*)d_in[1];
  const float* w_hh = (const float*)d_in[2];
  const float* b_ih = (const float*)d_in[3];
  const float* b_hh = (const float*)d_in[4];
  const float* h0   = (const float*)d_in[5];
  const float* c0   = (const float*)d_in[6];
  float* out = (float*)d_out;

  // workspace layout (bytes); total ~156.3 MB
  char* ws = (char*)d_ws;
  unsigned* flags = (unsigned*)ws;                       // 1 KB (128 used)
  _Float16* hbuf  = (_Float16*)(ws + 1024);              // 2*64*1024*2 = 256 KB
  _Float16* whhq  = (_Float16*)(ws + 263168);            // 4096*1024*2 = 8 MB
  _Float16* wihq  = (_Float16*)(ws + 8651776);           // 4096*512*2  = 4 MB
  float*    bihq  = (float*)(ws + 12846080);             // 16 KB
  float*    bhhq  = (float*)(ws + 12862464);             // 16 KB
  _Float16* xq    = (_Float16*)(ws + 12878848);          // 16384*512*2 = 16 MB
  _Float16* gxb   = (_Float16*)(ws + 29656064);          // 128 MB packed

  hipMemsetAsync(flags, 0, 1024, stream);
  qf16_kernel<<<dim3(4096), 256, 0, stream>>>(w_hh, whhq, 4194304 / 4);
  qf16_kernel<<<dim3(2048), 256, 0, stream>>>(w_ih, wihq, 2097152 / 4);
  qx_kernel<<<dim3(8192), 256, 0, stream>>>(x, xq);
  qf16_kernel<<<dim3(64), 256, 0, stream>>>(h0, hbuf, 65536 / 4);  // h buffer 0
  qf32_kernel<<<dim3(4), 256, 0, stream>>>(b_ih, bihq, 4096 / 4);
  qf32_kernel<<<dim3(4), 256, 0, stream>>>(b_hh, bhhq, 4096 / 4);
  gemm_gx_kernel<<<dim3(128, 32), 256, 0, stream>>>(xq, wihq, bihq, gxb);
  lstm_kernel<<<dim3(128), 256, 0, stream>>>(whhq, bhhq, gxb, c0, hbuf, out,
                                             flags);
}

// Round 3
// 3741.465 us; speedup vs baseline: 1.4886x; 1.4327x over previous
//
#include <hip/hip_runtime.h>
#include <stdint.h>

// ---------------------------------------------------------------------------
// FixedPointLSTM (B=64, T=256, I=512, H=1024), fixed-point Q8.8 with hard
// activations. All fxp grid values are exactly representable in fp16; fp16
// MFMA with fp32 accumulate matches the numpy reference to ~1 grid step.
//
// R3: kill the per-step coherence stall. (a) h is communicated entirely via
// agent-scope relaxed atomics BOTH ways (stores bypass L2 to the coherence
// point; loads read it directly) -> no acquire fence / buffer_inv per step,
// L2 keeps the gx stream warm. (b) s_sleep(16) backoff in the flag poll so
// 128 spinning waves stop hammering the flag lines and delaying the very
// release stores they wait on.
// ---------------------------------------------------------------------------

typedef _Float16 h8 __attribute__((ext_vector_type(8)));
typedef _Float16 h4 __attribute__((ext_vector_type(4)));
typedef float f4 __attribute__((ext_vector_type(4)));
typedef unsigned long long u64;
typedef u64 u64x2 __attribute__((ext_vector_type(2)));

#define MFMA16(a, b, c) __builtin_amdgcn_mfma_f32_16x16x32_f16(a, b, c, 0, 0, 0)

__device__ __forceinline__ float fxp(float x) {
  float q = rintf(x * 256.0f) * 0.00390625f;
  return fminf(fmaxf(q, -128.0f), 127.99609375f);
}

__device__ __forceinline__ float hsig(float x) {
  return fminf(fmaxf(x / 6.0f + 0.5f, 0.0f), 1.0f);  // IEEE div to match np
}

// ---- quantize fp32 -> fxp grid, store fp16 ---------------------------------
__global__ void qf16_kernel(const float* __restrict__ in,
                            _Float16* __restrict__ out, int n4) {
  int i = blockIdx.x * 256 + threadIdx.x;
  if (i < n4) {
    float4 v = ((const float4*)in)[i];
    h4 o;
    o[0] = (_Float16)fxp(v.x); o[1] = (_Float16)fxp(v.y);
    o[2] = (_Float16)fxp(v.z); o[3] = (_Float16)fxp(v.w);
    ((h4*)out)[i] = o;
  }
}

// quantize + transpose x: in [64][256][512] -> out rows m = t*64+b, [16384][512]
__global__ void qx_kernel(const float* __restrict__ in,
                          _Float16* __restrict__ out) {
  int i4 = blockIdx.x * 256 + threadIdx.x;  // over 16384*128 float4s
  int col4 = i4 & 127;
  int row = i4 >> 7;  // b*256 + t
  int b = row >> 8, tt = row & 255;
  float4 v = ((const float4*)in)[i4];
  h4 o;
  o[0] = (_Float16)fxp(v.x); o[1] = (_Float16)fxp(v.y);
  o[2] = (_Float16)fxp(v.z); o[3] = (_Float16)fxp(v.w);
  ((h4*)out)[(size_t)((tt << 6) + b) * 128 + col4] = o;
}

__global__ void qf32_kernel(const float* __restrict__ in,
                            float* __restrict__ out, int n4) {
  int i = blockIdx.x * 256 + threadIdx.x;
  if (i < n4) {
    float4 v = ((const float4*)in)[i];
    float4 o;
    o.x = fxp(v.x); o.y = fxp(v.y); o.z = fxp(v.z); o.w = fxp(v.w);
    ((float4*)out)[i] = o;
  }
}

// ---- async global->LDS helper (width 16B; LDS dest = wave-uniform base) ----
__device__ __forceinline__ void gload_lds16(const _Float16* g, _Float16* l) {
  __builtin_amdgcn_global_load_lds(
      (const __attribute__((address_space(1))) uint32_t*)g,
      (__attribute__((address_space(3))) uint32_t*)l, 16, 0, 0);
}

// ---------------------------------------------------------------------------
// gx = fxp(x_q @ w_ih_q^T + b_ih_q), packed [T=256][blk=128][tid=256][8] fp16.
// M=16384 (m = t*64+b), N=4096, K=512. m97-style 128x128 tile, BK=32.
// ---------------------------------------------------------------------------
__global__ __launch_bounds__(256) void gemm_gx_kernel(
    const _Float16* __restrict__ Xq,   // [16384][512], m = t*64+b
    const _Float16* __restrict__ Wih,  // [4096][512]
    const float* __restrict__ bih,     // [4096]
    _Float16* __restrict__ gx)         // packed, see above
{
  __shared__ _Float16 As[128 * 32];
  __shared__ _Float16 Bs[128 * 32];
  const int tid = threadIdx.x;
  const int lane = tid & 63;
  const int w = tid >> 6;
  const int wm = (w >> 1) * 64;
  const int wn = (w & 1) * 64;
  const int m0 = blockIdx.x * 128;
  const int n0 = blockIdx.y * 128;
  const int cl = lane & 15, q = lane >> 4;

  f4 acc[4][4] = {};

  for (int k0 = 0; k0 < 512; k0 += 32) {
#pragma unroll
    for (int i = 0; i < 2; i++) {
      int idx = i * 256 + tid;
      int row = idx >> 2;
      int kc = (idx & 3) << 3;
      int wbase = (i * 256 + (tid & 192)) << 3;  // wave-uniform LDS base
      gload_lds16(Xq + (size_t)(m0 + row) * 512 + k0 + kc, As + wbase);
      gload_lds16(Wih + (size_t)(n0 + row) * 512 + k0 + kc, Bs + wbase);
    }
    __syncthreads();
    h8 af[4], bf[4];
#pragma unroll
    for (int mt = 0; mt < 4; mt++)
      af[mt] = *(const h8*)(As + (wm + mt * 16 + cl) * 32 + q * 8);
#pragma unroll
    for (int nt = 0; nt < 4; nt++)
      bf[nt] = *(const h8*)(Bs + (wn + nt * 16 + cl) * 32 + q * 8);
#pragma unroll
    for (int mt = 0; mt < 4; mt++)
#pragma unroll
      for (int nt = 0; nt < 4; nt++)
        acc[mt][nt] = MFMA16(af[mt], bf[nt], acc[mt][nt]);
    __syncthreads();
  }

  const int g = n0 >> 10;           // whole n-block lies in one gate
  const int tile = g >> 1;
#pragma unroll
  for (int nt = 0; nt < 4; nt++) {
    const int n = n0 + wn + nt * 16 + cl;
    const float bv = bih[n];
    const int j = n & 1023;
    const int blk = j >> 3;
    const int cl2 = ((g & 1) << 3) | (j & 7);
#pragma unroll
    for (int mt = 0; mt < 4; mt++) {
      const int mb = wm + mt * 16 + q * 4;  // m = m0+mb+r, 4-aligned
      const int m = m0 + mb;
      const int b = m & 63, tt = m >> 6;    // b 4-aligned; r2 = r
      const int tid2 = ((b >> 4) << 6) | (((b >> 2) & 3) << 4) | cl2;
      h4 pk;
#pragma unroll
      for (int r = 0; r < 4; r++) pk[r] = (_Float16)fxp(acc[mt][nt][r] + bv);
      *(h4*)(gx + ((((size_t)tt * 128 + blk) * 256 + tid2) << 3) + (tile << 2)) = pk;
    }
  }
}

// ---------------------------------------------------------------------------
// Persistent recurrence kernel. 128 blocks x 256 threads (4 waves, 1/SIMD).
// Block b owns h-columns j0..j0+7 across all 4 gates (32 W_hh rows) held in
// registers for all 256 steps. Wave w handles batch rows w*16..w*16+15.
// Sync per step: block release-stores t+1 to flags[blk]; wave 0 polls all
// 128 flags with s_sleep backoff. h moves via agent-scope relaxed atomics
// both directions (coherence-point traffic, no fences, L2 untouched).
// ---------------------------------------------------------------------------
__global__ __launch_bounds__(256, 1) void lstm_kernel(
    const _Float16* __restrict__ Whh,  // [4096][1024] quantized
    const float* __restrict__ bhh,     // [4096] quantized
    const _Float16* __restrict__ gx,   // packed [256][128][256][8]
    const float* __restrict__ c0,      // [64][1024]
    _Float16* __restrict__ hbuf,       // [2][64][1024]
    float* __restrict__ out,           // [64][256][1024] ++ h_n ++ c_n
    unsigned* __restrict__ flags)      // [128]
{
  const int tid = threadIdx.x;
  const int lane = tid & 63;
  const int w = tid >> 6;
  const int cl = lane & 15, q = lane >> 4;
  const int j0 = blockIdx.x << 3;
  const int g01 = cl >> 3;
  const int row0 = (g01 << 10) + j0 + (cl & 7);        // gates i/f
  const int row1 = ((g01 + 2) << 10) + j0 + (cl & 7);  // gates g/o

  // persistent B fragments: 2 tiles x 32 k-steps x 4 regs = 256 regs
  h8 B0[32], B1[32];
#pragma unroll
  for (int kt = 0; kt < 32; kt++) {
    B0[kt] = *(const h8*)(Whh + (size_t)row0 * 1024 + (kt << 5) + (q << 3));
    B1[kt] = *(const h8*)(Whh + (size_t)row1 * 1024 + (kt << 5) + (q << 3));
  }
  const float bh0 = bhh[row0], bh1 = bhh[row1];
  const int jc = j0 + (lane & 7);
  const int mrow = (w << 4) + (q << 2);
  const int arow = (w << 4) + cl;
  const bool writer = (lane & 8) == 0;

  float c_st[4], h_last[4];
#pragma unroll
  for (int r = 0; r < 4; r++) {
    c_st[r] = c0[(mrow + r) * 1024 + jc];
    h_last[r] = 0.0f;
  }

  const u64* hb64base = (const u64*)hbuf;
  const size_t bi0 = (size_t)arow * 256 + (q << 1);  // u64 index within buffer

  for (int t = 0; t < 256; t++) {
    // prefetch gx_t: one coalesced 16B load per lane (overlaps the spin)
    const h8 gv8 =
        *(const h8*)(gx + ((((size_t)t * 128 + blockIdx.x) * 256 + tid) << 3));

    if (t) {
      if (w == 0) {
        const u64* f2 = (const u64*)flags;
        const unsigned tt = (unsigned)t;
        for (;;) {
          u64 v = __hip_atomic_load(&f2[lane], __ATOMIC_RELAXED,
                                    __HIP_MEMORY_SCOPE_AGENT);
          bool ok = ((unsigned)v >= tt) && ((unsigned)(v >> 32) >= tt);
          if (__ballot(ok) == ~0ull) break;
          __builtin_amdgcn_s_sleep(16);  // ~1k cyc backoff: don't melt fabric
        }
      }
      __syncthreads();
      // no fence: h loads below are agent-scope atomics (cache-bypassing)
    }

    const u64* hb64 = hb64base + ((size_t)(t & 1) << 14);  // 64*1024*2B/8
    f4 a0 = {}, a1 = {}, a2 = {}, a3 = {};
#pragma unroll
    for (int kt = 0; kt < 32; kt++) {
      u64x2 p;
      p[0] = __hip_atomic_load(hb64 + bi0 + (kt << 3), __ATOMIC_RELAXED,
                               __HIP_MEMORY_SCOPE_AGENT);
      p[1] = __hip_atomic_load(hb64 + bi0 + (kt << 3) + 1, __ATOMIC_RELAXED,
                               __HIP_MEMORY_SCOPE_AGENT);
      h8 av = __builtin_bit_cast(h8, p);
      if (kt & 1) { a1 = MFMA16(av, B0[kt], a1); a3 = MFMA16(av, B1[kt], a3); }
      else        { a0 = MFMA16(av, B0[kt], a0); a2 = MFMA16(av, B1[kt], a2); }
    }
    f4 g0 = a0 + a1;
    f4 g1 = a2 + a3;

    _Float16* hw = hbuf + (((t + 1) & 1) << 16);
#pragma unroll
    for (int r = 0; r < 4; r++) {
      float gv0 = fxp((float)gv8[r] + fxp(g0[r] + bh0));      // i or f
      float gv1 = fxp((float)gv8[4 + r] + fxp(g1[r] + bh1));  // g or o
      float s0 = fxp(hsig(gv0));
      float s1t = fxp(fminf(fmaxf(gv1, -1.0f), 1.0f));
      float s1s = fxp(hsig(gv1));
      float s1 = (lane & 8) ? s1s : s1t;
      float p0 = __shfl_xor(s0, 8);
      float p1 = __shfl_xor(s1, 8);
      float iv = writer ? s0 : p0;
      float fv = writer ? p0 : s0;
      float gv = writer ? s1 : p1;
      float ov = writer ? p1 : s1;
      float cn = fxp(fv * c_st[r] + iv * gv);
      c_st[r] = cn;
      float hn = fxp(ov * fminf(fmaxf(cn, -1.0f), 1.0f));
      h_last[r] = hn;
      if (writer) {
        unsigned short hbits = __builtin_bit_cast(unsigned short, (_Float16)hn);
        __hip_atomic_store((unsigned short*)&hw[(size_t)(mrow + r) * 1024 + jc],
                           hbits, __ATOMIC_RELAXED, __HIP_MEMORY_SCOPE_AGENT);
        __builtin_nontemporal_store(
            hn, &out[((size_t)(mrow + r) * 256 + t) * 1024 + jc]);
      }
    }
    __syncthreads();  // drains all waves' stores (vmcnt(0) before s_barrier)
    if (tid == 0)
      __hip_atomic_store(&flags[blockIdx.x], (unsigned)(t + 1),
                         __ATOMIC_RELEASE, __HIP_MEMORY_SCOPE_AGENT);
  }

  if (writer) {
#pragma unroll
    for (int r = 0; r < 4; r++) {
      out[16777216 + (size_t)(mrow + r) * 1024 + jc] = h_last[r];        // h_n
      out[16777216 + 65536 + (size_t)(mrow + r) * 1024 + jc] = c_st[r];  // c_n
    }
  }
}

// ---------------------------------------------------------------------------
extern "C" void kernel_launch(void* const* d_in, const int* in_sizes, int n_in,
                              void* d_out, int out_size, void* d_ws,
                              size_t ws_size, hipStream_t stream) {
  const float* x    = (const float*)d_in[0];
  const float* w_ih = (const float*)d_in[1];
  const float* w_hh = (const float*)d_in[2];
  const float* b_ih = (const float*)d_in[3];
  const float* b_hh = (const float*)d_in[4];
  const float* h0   = (const float*)d_in[5];
  const float* c0   = (const float*)d_in[6];
  float* out = (float*)d_out;

  // workspace layout (bytes); total ~156.3 MB
  char* ws = (char*)d_ws;
  unsigned* flags = (unsigned*)ws;                       // 1 KB (128 used)
  _Float16* hbuf  = (_Float16*)(ws + 1024);              // 2*64*1024*2 = 256 KB
  _Float16* whhq  = (_Float16*)(ws + 263168);            // 4096*1024*2 = 8 MB
  _Float16* wihq  = (_Float16*)(ws + 8651776);           // 4096*512*2  = 4 MB
  float*    bihq  = (float*)(ws + 12846080);             // 16 KB
  float*    bhhq  = (float*)(ws + 12862464);             // 16 KB
  _Float16* xq    = (_Float16*)(ws + 12878848);          // 16384*512*2 = 16 MB
  _Float16* gxb   = (_Float16*)(ws + 29656064);          // 128 MB packed

  hipMemsetAsync(flags, 0, 1024, stream);
  qf16_kernel<<<dim3(4096), 256, 0, stream>>>(w_hh, whhq, 4194304 / 4);
  qf16_kernel<<<dim3(2048), 256, 0, stream>>>(w_ih, wihq, 2097152 / 4);
  qx_kernel<<<dim3(8192), 256, 0, stream>>>(x, xq);
  qf16_kernel<<<dim3(64), 256, 0, stream>>>(h0, hbuf, 65536 / 4);  // h buffer 0
  qf32_kernel<<<dim3(4), 256, 0, stream>>>(b_ih, bihq, 4096 / 4);
  qf32_kernel<<<dim3(4), 256, 0, stream>>>(b_hh, bhhq, 4096 / 4);
  gemm_gx_kernel<<<dim3(128, 32), 256, 0, stream>>>(xq, wihq, bihq, gxb);
  lstm_kernel<<<dim3(128), 256, 0, stream>>>(whhq, bhhq, gxb, c0, hbuf, out,
                                             flags);
}

// Round 6
// 1268.072 us; speedup vs baseline: 4.3922x; 2.9505x over previous
//
#include <hip/hip_runtime.h>
#include <stdint.h>

// ---------------------------------------------------------------------------
// FixedPointLSTM (B=64, T=256, I=512, H=1024), fixed-point Q8.8 with hard
// activations. All fxp grid values are exactly representable in fp16; fp16
// MFMA with fp32 accumulate matches the numpy reference to ~1 grid step.
//
// R6: deterministic 32-block groups (grp = blockIdx&7 owns batch octet,
// rank = blockIdx>>3 owns 32 h-columns x 4 gates held in 256 regs/wave).
// ALL cross-block communication uses agent-scope relaxed atomics (IC
// coherence point) — correct under any block placement and any L1 policy
// (R4/R5's plain-store + sc0-load XCD-local protocol failed; R3 proved the
// atomic path). h staged cooperatively: 8x coalesced 8B atomic loads/thread
// into LDS (16 KB/block/step vs R3's 128 KB/block/step per-lane scatter).
// a255 pin -> 1 wave/SIMD -> 1 block/CU -> all 256 blocks co-resident.
// ---------------------------------------------------------------------------

typedef _Float16 h8 __attribute__((ext_vector_type(8)));
typedef _Float16 h4 __attribute__((ext_vector_type(4)));
typedef float f4 __attribute__((ext_vector_type(4)));
typedef unsigned long long u64;

#define MFMA16(a, b, c) __builtin_amdgcn_mfma_f32_16x16x32_f16(a, b, c, 0, 0, 0)

__device__ __forceinline__ float fxp(float x) {
  float q = rintf(x * 256.0f) * 0.00390625f;
  return fminf(fmaxf(q, -128.0f), 127.99609375f);
}

__device__ __forceinline__ float hsig(float x) {
  return fminf(fmaxf(x / 6.0f + 0.5f, 0.0f), 1.0f);  // IEEE div to match np
}

// ---- quantize fp32 -> fxp grid, store fp16 ---------------------------------
__global__ void qf16_kernel(const float* __restrict__ in,
                            _Float16* __restrict__ out, int n4) {
  int i = blockIdx.x * 256 + threadIdx.x;
  if (i < n4) {
    float4 v = ((const float4*)in)[i];
    h4 o;
    o[0] = (_Float16)fxp(v.x); o[1] = (_Float16)fxp(v.y);
    o[2] = (_Float16)fxp(v.z); o[3] = (_Float16)fxp(v.w);
    ((h4*)out)[i] = o;
  }
}

// quantize + transpose x: in [64][256][512] -> rows m = t*64+b, [16384][512]
__global__ void qx_kernel(const float* __restrict__ in,
                          _Float16* __restrict__ out) {
  int i4 = blockIdx.x * 256 + threadIdx.x;  // over 16384*128 float4s
  int col4 = i4 & 127;
  int row = i4 >> 7;  // b*256 + t
  int b = row >> 8, tt = row & 255;
  float4 v = ((const float4*)in)[i4];
  h4 o;
  o[0] = (_Float16)fxp(v.x); o[1] = (_Float16)fxp(v.y);
  o[2] = (_Float16)fxp(v.z); o[3] = (_Float16)fxp(v.w);
  ((h4*)out)[(size_t)((tt << 6) + b) * 128 + col4] = o;
}

__global__ void qf32_kernel(const float* __restrict__ in,
                            float* __restrict__ out, int n4) {
  int i = blockIdx.x * 256 + threadIdx.x;
  if (i < n4) {
    float4 v = ((const float4*)in)[i];
    float4 o;
    o.x = fxp(v.x); o.y = fxp(v.y); o.z = fxp(v.z); o.w = fxp(v.w);
    ((float4*)out)[i] = o;
  }
}

// h0 -> hbuf buffer 0, layout [grp=8][buf=2][row=8][1024] fp16
__global__ void qh0_kernel(const float* __restrict__ in,
                           _Float16* __restrict__ hbuf) {
  int i = blockIdx.x * 256 + threadIdx.x;  // over 64*1024/4
  int col4 = i & 255, b = i >> 8;
  float4 v = ((const float4*)in)[i];
  h4 o;
  o[0] = (_Float16)fxp(v.x); o[1] = (_Float16)fxp(v.y);
  o[2] = (_Float16)fxp(v.z); o[3] = (_Float16)fxp(v.w);
  *(h4*)(hbuf + (size_t)(b >> 3) * 16384 + (b & 7) * 1024 + col4 * 4) = o;
}

// ---- async global->LDS helper (width 16B; LDS dest = wave-uniform base) ----
__device__ __forceinline__ void gload_lds16(const _Float16* g, _Float16* l) {
  __builtin_amdgcn_global_load_lds(
      (const __attribute__((address_space(1))) uint32_t*)g,
      (__attribute__((address_space(3))) uint32_t*)l, 16, 0, 0);
}

// ---------------------------------------------------------------------------
// gx = fxp(x_q @ w_ih_q^T + b_ih_q), packed [T=256][oct=8][rank=32][slot=128][8]
// fp16 (128 MB). slot = (w<<5)|(qh<<4)|(gate&1)<<3|(j&7); per-entry 8 fp16 =
// [tile0 r=0..3 | tile1 r=0..3], tile = gate>>1, r = b&3, qh = (b>>2)&1.
// ---------------------------------------------------------------------------
__global__ __launch_bounds__(256) void gemm_gx_kernel(
    const _Float16* __restrict__ Xq,   // [16384][512], m = t*64+b
    const _Float16* __restrict__ Wih,  // [4096][512]
    const float* __restrict__ bih,     // [4096]
    _Float16* __restrict__ gx)         // packed, see above
{
  __shared__ _Float16 As[128 * 32];
  __shared__ _Float16 Bs[128 * 32];
  const int tid = threadIdx.x;
  const int lane = tid & 63;
  const int w = tid >> 6;
  const int wm = (w >> 1) * 64;
  const int wn = (w & 1) * 64;
  const int m0 = blockIdx.x * 128;
  const int n0 = blockIdx.y * 128;
  const int cl = lane & 15, q = lane >> 4;

  f4 acc[4][4] = {};

  for (int k0 = 0; k0 < 512; k0 += 32) {
#pragma unroll
    for (int i = 0; i < 2; i++) {
      int idx = i * 256 + tid;
      int row = idx >> 2;
      int kc = (idx & 3) << 3;
      int wbase = (i * 256 + (tid & 192)) << 3;  // wave-uniform LDS base
      gload_lds16(Xq + (size_t)(m0 + row) * 512 + k0 + kc, As + wbase);
      gload_lds16(Wih + (size_t)(n0 + row) * 512 + k0 + kc, Bs + wbase);
    }
    __syncthreads();
    h8 af[4], bf[4];
#pragma unroll
    for (int mt = 0; mt < 4; mt++)
      af[mt] = *(const h8*)(As + (wm + mt * 16 + cl) * 32 + q * 8);
#pragma unroll
    for (int nt = 0; nt < 4; nt++)
      bf[nt] = *(const h8*)(Bs + (wn + nt * 16 + cl) * 32 + q * 8);
#pragma unroll
    for (int mt = 0; mt < 4; mt++)
#pragma unroll
      for (int nt = 0; nt < 4; nt++)
        acc[mt][nt] = MFMA16(af[mt], bf[nt], acc[mt][nt]);
    __syncthreads();
  }

  const int g = n0 >> 10;  // whole n-block lies in one gate
  const int tile = g >> 1, g1 = g & 1;
#pragma unroll
  for (int nt = 0; nt < 4; nt++) {
    const int n = n0 + wn + nt * 16 + cl;
    const float bv = bih[n];
    const int j = n & 1023;
    const int rank = j >> 5, wq = (j >> 3) & 3, c7 = j & 7;
#pragma unroll
    for (int mt = 0; mt < 4; mt++) {
      const int m = m0 + wm + mt * 16 + q * 4;  // 4-aligned
      const int b = m & 63, tt = m >> 6;
      const int oct = b >> 3, qh = (b >> 2) & 1;
      const int slot = (wq << 5) | (qh << 4) | (g1 << 3) | c7;
      h4 pk;
#pragma unroll
      for (int r = 0; r < 4; r++) pk[r] = (_Float16)fxp(acc[mt][nt][r] + bv);
      *(h4*)(gx + ((((size_t)tt * 8 + oct) * 32 + rank) * 128 + slot) * 8 +
             tile * 4) = pk;
    }
  }
}

// ---------------------------------------------------------------------------
// Persistent recurrence. 256 blocks x 256 threads, a255 pin -> 1 block/CU ->
// all blocks co-resident. Block = (grp = blockIdx&7, rank = blockIdx>>3);
// group grp owns batch rows 8g..8g+7; rank owns h-cols rank*32..+31 x 4
// gates (128 W_hh rows in 256 regs/wave). Per step: stage group h (16KB)
// via 8B agent atomic loads -> LDS, MFMA, gate math, h out via 2B agent
// atomic stores, flag via agent atomic store after barrier drain; poll 32
// group flags via 8B agent atomic loads with s_sleep backoff.
// ---------------------------------------------------------------------------
__global__ __launch_bounds__(256, 1) void lstm_kernel(
    const _Float16* __restrict__ Whh,  // [4096][1024] quantized
    const float* __restrict__ bhh,     // [4096] quantized
    const _Float16* __restrict__ gx,   // packed [256][8][32][128][8]
    const float* __restrict__ c0,      // [64][1024]
    _Float16* __restrict__ hbuf,       // [8][2][8][1024] fp16
    float* __restrict__ out,           // [64][256][1024] ++ h_n ++ c_n
    unsigned* __restrict__ flags)      // [8][32]
{
  // Residency pin: force total regs/wave > 256 -> 1 wave/SIMD -> 1 block/CU.
  asm volatile("v_accvgpr_write_b32 a255, 0" ::: "a255");

  const int tid = threadIdx.x;
  const int lane = tid & 63;
  const int w = tid >> 6;
  const int cl = lane & 15, q = lane >> 4;
  const int g01 = (lane >> 3) & 1;
  const int c7 = lane & 7;

  const int grp = blockIdx.x & 7;      // batch octet (== XCD if round-robin)
  const int rank = blockIdx.x >> 3;    // 32-column slice owner

  const int jbase = (rank << 5) + (w << 3);            // block/wave col base
  const int row0 = (g01 << 10) + jbase + c7;           // gates i/f
  const int row1 = ((g01 + 2) << 10) + jbase + c7;     // gates g/o

  // persistent B fragments: 2 tiles x 32 k-steps x 4 regs = 256 regs
  h8 B0[32], B1[32];
#pragma unroll
  for (int kt = 0; kt < 32; kt++) {
    B0[kt] = *(const h8*)(Whh + (size_t)row0 * 1024 + (kt << 5) + (q << 3));
    B1[kt] = *(const h8*)(Whh + (size_t)row1 * 1024 + (kt << 5) + (q << 3));
  }
  const float bh0 = bhh[row0], bh1 = bhh[row1];
  const int jc = jbase + c7;                 // h column 0..1023
  const int lrow = ((q & 1) << 2);           // local batch row base (q<2)
  const bool writer = ((lane & 8) == 0) && (q < 2);

  float c_st[4], h_last[4];
#pragma unroll
  for (int r = 0; r < 4; r++) {
    c_st[r] = c0[((grp << 3) + lrow + r) * 1024 + jc];
    h_last[r] = 0.0f;
  }

  // LDS h stage: 8 rows x 1032 fp16 (pad +8 breaks bank repeat)
  __shared__ alignas(16) _Float16 hs[8 * 1032];
  const int srow = tid >> 5, scol = (tid & 31) << 5;  // 32 halves per thread
  _Float16* hsp = hs + srow * 1032 + scol;
  const int arow = cl & 7;

  // u64 views for agent-atomic staging / polling
  const u64* hb64 = (const u64*)hbuf;             // [grp:4096][buf:2048] u64s
  const size_t stg0 = (size_t)grp * 4096 + (size_t)tid * 8;
  unsigned* myflag = flags + (grp << 5) + rank;
  const u64* f2 = (const u64*)(flags + (grp << 5));  // 16 u64 per group

  for (int t = 0; t < 256; t++) {
    // prefetch gx_t: one coalesced 16B load per lane (overlaps the wait)
    const h8 gv8 = *(const h8*)(
        gx +
        ((((size_t)t * 8 + grp) * 32 + rank) * 128 + ((w << 5) | (lane & 31))) *
            8);

    if (t) {
      if (w == 0) {
        const unsigned tt = (unsigned)t;
        int it = 0;
        for (;;) {
          u64 v = __hip_atomic_load(&f2[lane & 15], __ATOMIC_RELAXED,
                                    __HIP_MEMORY_SCOPE_AGENT);
          bool ok = ((unsigned)v >= tt) && ((unsigned)(v >> 32) >= tt);
          if (__ballot(ok) == ~0ull) break;
          if (++it > (1 << 17)) break;  // hang insurance (loudly wrong)
          __builtin_amdgcn_s_sleep(1);
        }
      }
      __syncthreads();
    }

    // stage h_t (group's 8x1024 fp16 = 16KB): 8 coalesced 8B agent loads
    {
      const u64* src = hb64 + stg0 + (size_t)(t & 1) * 2048;
      u64 v0 = __hip_atomic_load(src + 0, __ATOMIC_RELAXED, __HIP_MEMORY_SCOPE_AGENT);
      u64 v1 = __hip_atomic_load(src + 1, __ATOMIC_RELAXED, __HIP_MEMORY_SCOPE_AGENT);
      u64 v2 = __hip_atomic_load(src + 2, __ATOMIC_RELAXED, __HIP_MEMORY_SCOPE_AGENT);
      u64 v3 = __hip_atomic_load(src + 3, __ATOMIC_RELAXED, __HIP_MEMORY_SCOPE_AGENT);
      u64 v4 = __hip_atomic_load(src + 4, __ATOMIC_RELAXED, __HIP_MEMORY_SCOPE_AGENT);
      u64 v5 = __hip_atomic_load(src + 5, __ATOMIC_RELAXED, __HIP_MEMORY_SCOPE_AGENT);
      u64 v6 = __hip_atomic_load(src + 6, __ATOMIC_RELAXED, __HIP_MEMORY_SCOPE_AGENT);
      u64 v7 = __hip_atomic_load(src + 7, __ATOMIC_RELAXED, __HIP_MEMORY_SCOPE_AGENT);
      u64* d = (u64*)hsp;
      d[0] = v0; d[1] = v1; d[2] = v2; d[3] = v3;
      d[4] = v4; d[5] = v5; d[6] = v6; d[7] = v7;
    }
    __syncthreads();

    f4 a0 = {}, a1 = {}, a2 = {}, a3 = {};
#pragma unroll
    for (int kt = 0; kt < 32; kt++) {
      h8 av = *(const h8*)(hs + arow * 1032 + (kt << 5) + (q << 3));
      if (kt & 1) { a1 = MFMA16(av, B0[kt], a1); a3 = MFMA16(av, B1[kt], a3); }
      else        { a0 = MFMA16(av, B0[kt], a0); a2 = MFMA16(av, B1[kt], a2); }
    }
    f4 g0 = a0 + a1;
    f4 g1 = a2 + a3;

    _Float16* hbw = hbuf + (size_t)grp * 16384 + ((t + 1) & 1) * 8192;
#pragma unroll
    for (int r = 0; r < 4; r++) {
      float gv0 = fxp((float)gv8[r] + fxp(g0[r] + bh0));      // i or f
      float gv1 = fxp((float)gv8[4 + r] + fxp(g1[r] + bh1));  // g or o
      float s0 = fxp(hsig(gv0));
      float s1t = fxp(fminf(fmaxf(gv1, -1.0f), 1.0f));
      float s1s = fxp(hsig(gv1));
      float s1 = (lane & 8) ? s1s : s1t;
      float p0 = __shfl_xor(s0, 8);
      float p1 = __shfl_xor(s1, 8);
      float iv = writer ? s0 : p0;
      float fv = writer ? p0 : s0;
      float gv = writer ? s1 : p1;
      float ov = writer ? p1 : s1;
      float cn = fxp(fv * c_st[r] + iv * gv);
      c_st[r] = cn;
      float hn = fxp(ov * fminf(fmaxf(cn, -1.0f), 1.0f));
      h_last[r] = hn;
      if (writer) {
        unsigned short hbits = __builtin_bit_cast(unsigned short, (_Float16)hn);
        __hip_atomic_store((unsigned short*)&hbw[(lrow + r) * 1024 + jc], hbits,
                           __ATOMIC_RELAXED, __HIP_MEMORY_SCOPE_AGENT);
        __builtin_nontemporal_store(
            hn, &out[((size_t)((grp << 3) + lrow + r) * 256 + t) * 1024 + jc]);
      }
    }
    __syncthreads();  // vmcnt(0) drain: h atomic stores acked at IC
    if (tid == 0)
      __hip_atomic_store(myflag, (unsigned)(t + 1), __ATOMIC_RELAXED,
                         __HIP_MEMORY_SCOPE_AGENT);
  }

  if (writer) {
#pragma unroll
    for (int r = 0; r < 4; r++) {
      out[16777216 + (size_t)((grp << 3) + lrow + r) * 1024 + jc] = h_last[r];
      out[16777216 + 65536 + (size_t)((grp << 3) + lrow + r) * 1024 + jc] =
          c_st[r];
    }
  }
}

// ---------------------------------------------------------------------------
extern "C" void kernel_launch(void* const* d_in, const int* in_sizes, int n_in,
                              void* d_out, int out_size, void* d_ws,
                              size_t ws_size, hipStream_t stream) {
  const float* x    = (const float*)d_in[0];
  const float* w_ih = (const float*)d_in[1];
  const float* w_hh = (const float*)d_in[2];
  const float* b_ih = (const float*)d_in[3];
  const float* b_hh = (const float*)d_in[4];
  const float* h0   = (const float*)d_in[5];
  const float* c0   = (const float*)d_in[6];
  float* out = (float*)d_out;

  // workspace layout (bytes); total ~156.3 MB
  char* ws = (char*)d_ws;
  unsigned* flags = (unsigned*)ws;                    // [8][32] u32 = 1 KB
  _Float16* hbuf  = (_Float16*)(ws + 2048);           // 8*2*8*1024*2 = 256 KB
  _Float16* whhq  = (_Float16*)(ws + 264192);         // 8 MB
  _Float16* wihq  = (_Float16*)(ws + 8652800);        // 4 MB
  float*    bihq  = (float*)(ws + 12847104);          // 16 KB
  float*    bhhq  = (float*)(ws + 12863488);          // 16 KB
  _Float16* xq    = (_Float16*)(ws + 12879872);       // 16 MB
  _Float16* gxb   = (_Float16*)(ws + 29657088);       // 128 MB packed

  hipMemsetAsync(flags, 0, 2048, stream);
  qf16_kernel<<<dim3(4096), 256, 0, stream>>>(w_hh, whhq, 4194304 / 4);
  qf16_kernel<<<dim3(2048), 256, 0, stream>>>(w_ih, wihq, 2097152 / 4);
  qx_kernel<<<dim3(8192), 256, 0, stream>>>(x, xq);
  qh0_kernel<<<dim3(64), 256, 0, stream>>>(h0, hbuf);
  qf32_kernel<<<dim3(4), 256, 0, stream>>>(b_ih, bihq, 4096 / 4);
  qf32_kernel<<<dim3(4), 256, 0, stream>>>(b_hh, bhhq, 4096 / 4);
  gemm_gx_kernel<<<dim3(128, 32), 256, 0, stream>>>(xq, wihq, bihq, gxb);
  lstm_kernel<<<dim3(256), 256, 0, stream>>>(whhq, bhhq, gxb, c0, hbuf, out,
                                             flags);
}